// Round 9
// baseline (265.381 us; speedup 1.0000x reference)
//
#include <hip/hip_runtime.h>
#include <hip/hip_bf16.h>

#define LN_EPS 1e-5f

typedef __bf16 bf16x8 __attribute__((ext_vector_type(8)));
typedef float  f32x4  __attribute__((ext_vector_type(4)));
typedef unsigned short u16;
typedef unsigned int u32;

__device__ __forceinline__ u16 f2bf(float f) {
    __bf16 b = (__bf16)f;
    return __builtin_bit_cast(u16, b);
}
__device__ __forceinline__ bf16x8 zero8() {
    bf16x8 v;
#pragma unroll
    for (int j = 0; j < 8; j++) v[j] = (__bf16)0.f;
    return v;
}
// tanh-form GELU: v * sigmoid(v*(1.59576912 + 0.07135482 v^2))
__device__ __forceinline__ float gelu_f(float v) {
    float t = v * fmaf(v * v, 0.0713548162726f, 1.5957691216057f);
    return v / (1.f + __expf(-t));
}

// ---------------------------------------------------------------------------
// prep: pack weights into bf16 MFMA B-fragment order (16x16x32).
// ---------------------------------------------------------------------------
__global__ __launch_bounds__(256) void prep_kernel(
    const float* __restrict__ qkv_w, const float* __restrict__ o1_w,
    const float* __restrict__ o2_w, u16* __restrict__ wq,
    u16* __restrict__ o1f, u16* __restrict__ o2f) {
    int i = blockIdx.x * 256 + threadIdx.x;
    if (i >= 81920) return;
    int j = i;
    const float* src;
    u16* dst;
    if (j < 49152) { src = qkv_w; dst = wq; }
    else if (j < 65536) { j -= 49152; src = o1_w; dst = o1f; }
    else { j -= 65536; src = o2_w; dst = o2f; }
    int jj = j & 7;
    int l  = (j >> 3) & 63;
    int s  = (j >> 9) & 3;
    int t  = j >> 11;
    int outc = t * 16 + (l & 15);
    int k    = s * 32 + ((l >> 4) & 3) * 8 + jj;
    dst[j] = f2bf(src[outc * 128 + k]);
}

// ---------------------------------------------------------------------------
// k1 (R9): R8 structure (4 barriers, x_a separate region), but kv partials
// now go through device-scope f32 atomicAdd into a 64KB L2-resident
// accumulator (kvacc[b][h][lane][4]) -- replaces the 16.8MB part write and
// the whole k_red kernel. 4 fire-and-forget atomics/lane, 16K distinct
// addresses, contention ~256/address spread over the dispatch.
// SESSION LAW: no loops / duplicated pipelines / reg-staging arrays across
// barriers -- R2, R4, R7 all spilled to scratch (+260..540MB sym traffic).
// grid 2048 = B * (N/64); block 512 (8 waves: 4 row-stripes x 2 head-halves)
// ---------------------------------------------------------------------------
__global__ __launch_bounds__(512, 8) void k1(
    const float* __restrict__ x, const u16* __restrict__ wq,
    const float* __restrict__ qkv_b,
    const float* __restrict__ klw, const float* __restrict__ klb,
    const float* __restrict__ vlw, const float* __restrict__ vlb,
    float* __restrict__ kvacc) {
    __shared__ __align__(16) char Rbuf[51200];
    u16* x_a  = (u16*)Rbuf;            // [64 n][136] @0..17408 (live to B3)
    u16* kv_s = (u16*)(Rbuf + 17408);  // [64 n][264] @17408..51200
    u16* kT   = (u16*)Rbuf;            // [128 hd][72] @0..18432 (post-B3)
    u16* vT   = (u16*)(Rbuf + 18432);  // [128 hd][72] @18432..36864 (post-B3)

    const int tid  = threadIdx.x;
    const int lane = tid & 63;
    const int wv   = tid >> 6;
    const int stripe = wv >> 1;
    const int half   = wv & 1;
    const int bid  = blockIdx.x;
    const int b    = bid >> 8;
    const int n0   = (bid & 255) * 64;

    // phase 1: stage x -> x_a, packed b32 writes (conflict-free)
    {
        int cw  = tid & 63;     // channel pair
        int sub = tid >> 6;     // n octet
        const float* p0 = x + ((size_t)(b * 128 + 2 * cw)) * 16384 + n0 + sub * 8;
        const float* p1 = p0 + 16384;
        float4 a0 = ((const float4*)p0)[0], a1 = ((const float4*)p0)[1];
        float4 c0 = ((const float4*)p1)[0], c1 = ((const float4*)p1)[1];
        float av[8] = {a0.x, a0.y, a0.z, a0.w, a1.x, a1.y, a1.z, a1.w};
        float cv[8] = {c0.x, c0.y, c0.z, c0.w, c1.x, c1.y, c1.z, c1.w};
        u32* dst = (u32*)x_a;
#pragma unroll
        for (int j = 0; j < 8; j++)
            dst[(sub * 8 + j) * 68 + cw] = (u32)f2bf(av[j]) | ((u32)f2bf(cv[j]) << 16);
    }
    __syncthreads();   // B1: x_a visible

    const int m16  = stripe * 16;
    const int l15  = lane & 15;
    const int quad = lane >> 4;

    // phase 2+3 (merged, no barrier between): A-frags from x_a, then k,v GEMM
    // writing kv_s -- disjoint LDS regions, so no sync needed.
    bf16x8 af[4];
#pragma unroll
    for (int s = 0; s < 4; s++)
        af[s] = *(const bf16x8*)&x_a[(m16 + l15) * 136 + s * 32 + quad * 8];

    const int tb = half * 12;
#pragma unroll
    for (int hh = 0; hh < 4; hh++) {
        const int tq = tb + 3 * hh;
        f32x4 ak  = (f32x4){0.f, 0.f, 0.f, 0.f};
        f32x4 avv = (f32x4){0.f, 0.f, 0.f, 0.f};
#pragma unroll
        for (int s = 0; s < 4; s++) {
            bf16x8 bk = *(const bf16x8*)(wq + (size_t)(((tq + 1) * 4 + s) * 64 + lane) * 8);
            bf16x8 bv = *(const bf16x8*)(wq + (size_t)(((tq + 2) * 4 + s) * 64 + lane) * 8);
            ak  = __builtin_amdgcn_mfma_f32_16x16x32_bf16(af[s], bk, ak, 0, 0, 0);
            avv = __builtin_amdgcn_mfma_f32_16x16x32_bf16(af[s], bv, avv, 0, 0, 0);
        }
        const int h = half * 4 + hh;
        float biask = qkv_b[(tq + 1) * 16 + l15];
        float biasv = qkv_b[(tq + 2) * 16 + l15];
#pragma unroll
        for (int r = 0; r < 4; r++) {
            int row = m16 + quad * 4 + r;
            kv_s[row * 264 + h * 32 + l15]      = f2bf(ak[r] + biask);
            kv_s[row * 264 + h * 32 + 16 + l15] = f2bf(avv[r] + biasv);
        }
    }
    __syncthreads();   // B2: kv_s visible

    // phase 4: per-row LN. thread = (head hL = wave, row = lane).
    const int hL = __builtin_amdgcn_readfirstlane(wv);
    const u16* rowp = &kv_s[lane * 264 + hL * 32];
    bf16x8 rk0 = *(const bf16x8*)(rowp);
    bf16x8 rk1 = *(const bf16x8*)(rowp + 8);
    bf16x8 rv0 = *(const bf16x8*)(rowp + 16);
    bf16x8 rv1 = *(const bf16x8*)(rowp + 24);
    __syncthreads();   // B3: kv_s (and x_a) dead -> kT/vT overlay safe

    {
        float kf[16], vf[16];
#pragma unroll
        for (int j = 0; j < 8; j++) {
            kf[j] = (float)rk0[j]; kf[8 + j] = (float)rk1[j];
            vf[j] = (float)rv0[j]; vf[8 + j] = (float)rv1[j];
        }
        float ksum = 0.f, ksq = 0.f, vsum = 0.f, vsq = 0.f;
#pragma unroll
        for (int d = 0; d < 16; d++) {
            ksum += kf[d]; ksq = fmaf(kf[d], kf[d], ksq);
            vsum += vf[d]; vsq = fmaf(vf[d], vf[d], vsq);
        }
        float km = ksum * (1.f / 16.f);
        float kvar = (ksq - 16.f * km * km) * (1.f / 15.f);
        kvar = kvar < 0.f ? 0.f : kvar;
        float kinv = 1.f / (sqrtf(kvar) + LN_EPS);
        float vm = vsum * (1.f / 16.f);
        float vvar = (vsq - 16.f * vm * vm) * (1.f / 15.f);
        vvar = vvar < 0.f ? 0.f : vvar;
        float vinv = 1.f / (sqrtf(vvar) + LN_EPS);
        const float* kwp = klw + hL * 16; const float* kbp = klb + hL * 16;
        const float* vwp = vlw + hL * 16; const float* vbp = vlb + hL * 16;
#pragma unroll
        for (int d = 0; d < 16; d++) {
            kT[(hL * 16 + d) * 72 + lane] = f2bf(fmaf((kf[d] - km) * kinv, kwp[d], kbp[d]));
            vT[(hL * 16 + d) * 72 + lane] = f2bf(fmaf((vf[d] - vm) * vinv, vwp[d], vbp[d]));
        }
    }
    __syncthreads();   // B4: kT/vT visible

    // phase 6: kv partial for head hL over all 64 rows: 2 MFMAs, then
    // 4 fire-and-forget f32 atomics into the 64KB L2-resident accumulator.
    {
        const u16* ka = &kT[(hL * 16 + l15) * 72 + quad * 8];
        const u16* vb = &vT[(hL * 16 + l15) * 72 + quad * 8];
        bf16x8 A0 = *(const bf16x8*)(ka);
        bf16x8 A1 = *(const bf16x8*)(ka + 32);
        bf16x8 B0 = *(const bf16x8*)(vb);
        bf16x8 B1 = *(const bf16x8*)(vb + 32);
        f32x4 kv = __builtin_amdgcn_mfma_f32_16x16x32_bf16(A0, B0, (f32x4){0.f,0.f,0.f,0.f}, 0, 0, 0);
        kv = __builtin_amdgcn_mfma_f32_16x16x32_bf16(A1, B1, kv, 0, 0, 0);
        float* dstp = kvacc + (size_t)(b * 8 + hL) * 256 + lane * 4;
#pragma unroll
        for (int r = 0; r < 4; r++)
            atomicAdd(dstp + r, kv[r]);
    }
}

// ---------------------------------------------------------------------------
// k2 (R9): R8 structure; kv B-frags built inline from the f32 kvacc
// accumulator (2 aligned float4 L2 loads + 8 cvt per head; x1/16384 scaling
// applied here, exactly where k_red applied it -> same rounding modulo
// atomic sum order). Weight B-frags stay as global loads (R7's LDS staging
// via reg arrays spilled: +313MB writes, VGPR 40->88).
// LDS 35840 (a_s 8704 + x_a16/h_s 8704 + x_s 18432), 4 blocks/CU, VGPR ~52.
// grid 4096 = B*(N/32); block 256 (2 stripes x 2 halves).
// ---------------------------------------------------------------------------
__global__ __launch_bounds__(256, 4) void k2(
    const float* __restrict__ x, const u16* __restrict__ wq,
    const float* __restrict__ qkv_b,
    const float* __restrict__ kvacc, const u16* __restrict__ o1f,
    const u16* __restrict__ o2f, const float* __restrict__ o1_b,
    const float* __restrict__ o2_b, float* __restrict__ out) {
    __shared__ u16 a_s[32 * 136];      // q -> ret (A-layout)
    __shared__ u16 x_a16[32 * 136];    // x A-layout; becomes h1 (h_s) later
    __shared__ float x_s[128 * 36];    // x [c][n]; becomes out in place

    u16* h_s = x_a16;                  // alias: h1 buffer (post-B2)

    const int tid  = threadIdx.x;
    const int lane = tid & 63;
    const int wv   = tid >> 6;
    const int stripe = wv >> 1;
    const int half   = wv & 1;
    const int bid  = blockIdx.x;
    const int b    = bid >> 9;
    const int n0   = (bid & 511) * 32;

    const int m16  = stripe * 16;
    const int l15  = lane & 15;
    const int quad = lane >> 4;
    const bool act = quad < 2;

    // hoisted kv B-frags from f32 accumulator (64KB, L2-resident).
    // frag elem j <-> (dk = quad*8+j, dv = l15); kvacc offset = lane'*4+r
    // with lane' = (dk>>2)*16+dv, r = dk&3  =>  j=0..3 and j=4..7 are two
    // CONSECUTIVE float4s at quad*128 + l15*4 (+64).
    bf16x8 kvb[4];
    {
        const float S = 1.f / 16384.f;
#pragma unroll
        for (int hh = 0; hh < 4; hh++) {
            int h = half * 4 + hh;
            if (act) {
                const float* kp = kvacc + (size_t)(b * 8 + h) * 256 + quad * 128 + l15 * 4;
                float4 lo = *(const float4*)(kp);
                float4 hi = *(const float4*)(kp + 64);
                bf16x8 kb;
                kb[0] = (__bf16)(lo.x * S); kb[1] = (__bf16)(lo.y * S);
                kb[2] = (__bf16)(lo.z * S); kb[3] = (__bf16)(lo.w * S);
                kb[4] = (__bf16)(hi.x * S); kb[5] = (__bf16)(hi.y * S);
                kb[6] = (__bf16)(hi.z * S); kb[7] = (__bf16)(hi.w * S);
                kvb[hh] = kb;
            } else {
                kvb[hh] = zero8();
            }
        }
    }

    // stage x -> x_s (f32, [c][n]) AND x_a16 (bf16 A-layout [n][136])
    {
        int cw  = tid & 63;     // channel pair
        int sub = tid >> 6;     // n octet (0..3)
        const float* p0 = x + ((size_t)(b * 128 + 2 * cw)) * 16384 + n0 + sub * 8;
        const float* p1 = p0 + 16384;
        float4 a0 = ((const float4*)p0)[0], a1 = ((const float4*)p0)[1];
        float4 c0 = ((const float4*)p1)[0], c1 = ((const float4*)p1)[1];
        float av[8] = {a0.x, a0.y, a0.z, a0.w, a1.x, a1.y, a1.z, a1.w};
        float cv[8] = {c0.x, c0.y, c0.z, c0.w, c1.x, c1.y, c1.z, c1.w};
        u32* da = (u32*)x_a16;
#pragma unroll
        for (int j = 0; j < 8; j++)
            da[(sub * 8 + j) * 68 + cw] = (u32)f2bf(av[j]) | ((u32)f2bf(cv[j]) << 16);
        float4* q0 = (float4*)&x_s[(2 * cw) * 36 + sub * 8];
        q0[0] = a0; q0[1] = a1;
        float4* q1 = (float4*)&x_s[(2 * cw + 1) * 36 + sub * 8];
        q1[0] = c0; q1[1] = c1;
    }
    __syncthreads();   // B1: x_s, x_a16 visible

    // q GEMM: reads x_a16 (cross-wave, covered by B1); q -> a_s own block
    {
        bf16x8 axf[4];
#pragma unroll
        for (int s = 0; s < 4; s++)
            axf[s] = *(const bf16x8*)&x_a16[(m16 + l15) * 136 + s * 32 + quad * 8];
#pragma unroll
        for (int hh = 0; hh < 4; hh++) {
            int h = half * 4 + hh;
            int tq = 3 * h;
            f32x4 aq = (f32x4){0.f, 0.f, 0.f, 0.f};
#pragma unroll
            for (int s = 0; s < 4; s++) {
                bf16x8 bq = *(const bf16x8*)(wq + (size_t)((tq * 4 + s) * 64 + lane) * 8);
                aq = __builtin_amdgcn_mfma_f32_16x16x32_bf16(axf[s], bq, aq, 0, 0, 0);
            }
            float biasq = qkv_b[tq * 16 + l15];
#pragma unroll
            for (int r = 0; r < 4; r++)
                a_s[(m16 + quad * 4 + r) * 136 + h * 16 + l15] = f2bf(aq[r] + biasq);
        }
    }
    // read back q A-frags (same-wave block: rows own stripe, cols own heads)
    bf16x8 qf[4];
#pragma unroll
    for (int hh = 0; hh < 4; hh++) {
        int h = half * 4 + hh;
        if (act) qf[hh] = *(const bf16x8*)&a_s[(m16 + l15) * 136 + h * 16 + quad * 8];
        else     qf[hh] = zero8();
    }

    // av per head (4 heads per wave), ret = av + x  (overwrites own a_s block)
#pragma unroll
    for (int hh = 0; hh < 4; hh++) {
        int h = half * 4 + hh;
        f32x4 acc = __builtin_amdgcn_mfma_f32_16x16x32_bf16(
            qf[hh], kvb[hh], (f32x4){0.f,0.f,0.f,0.f}, 0, 0, 0);
#pragma unroll
        for (int r = 0; r < 4; r++) {
            float rv = acc[r] + x_s[(h * 16 + l15) * 36 + m16 + quad * 4 + r];
            a_s[(m16 + quad * 4 + r) * 136 + h * 16 + l15] = f2bf(rv);
        }
    }
    __syncthreads();   // B2: a_s = ret visible; x_a16 reads all done

    // o1: 4 t-tiles per wave over full-128 rows; h1 -> h_s (retired x_a16)
    bf16x8 af2[4];
#pragma unroll
    for (int s = 0; s < 4; s++)
        af2[s] = *(const bf16x8*)&a_s[(m16 + l15) * 136 + s * 32 + quad * 8];
    f32x4 acc2[4];
#pragma unroll
    for (int t = 0; t < 4; t++) acc2[t] = (f32x4){0.f,0.f,0.f,0.f};
#pragma unroll
    for (int tt = 0; tt < 4; tt++) {
        int t = half * 4 + tt;
#pragma unroll
        for (int s = 0; s < 4; s++) {
            bf16x8 bf = *(const bf16x8*)(o1f + (size_t)((t * 4 + s) * 64 + lane) * 8);
            acc2[tt] = __builtin_amdgcn_mfma_f32_16x16x32_bf16(af2[s], bf, acc2[tt], 0, 0, 0);
        }
    }
#pragma unroll
    for (int tt = 0; tt < 4; tt++) {
        float bb = o1_b[(half * 4 + tt) * 16 + l15];
#pragma unroll
        for (int r = 0; r < 4; r++) {
            float gg = gelu_f(acc2[tt][r] + bb);
            h_s[(m16 + quad * 4 + r) * 136 + (half * 4 + tt) * 16 + l15] = f2bf(gg);
        }
    }
    __syncthreads();   // B3: h_s visible

    // o2: out = h1 @ o2^T + b2 + x  (in place in x_s)
#pragma unroll
    for (int s = 0; s < 4; s++)
        af2[s] = *(const bf16x8*)&h_s[(m16 + l15) * 136 + s * 32 + quad * 8];
#pragma unroll
    for (int t = 0; t < 4; t++) acc2[t] = (f32x4){0.f,0.f,0.f,0.f};
#pragma unroll
    for (int tt = 0; tt < 4; tt++) {
        int t = half * 4 + tt;
#pragma unroll
        for (int s = 0; s < 4; s++) {
            bf16x8 bf = *(const bf16x8*)(o2f + (size_t)((t * 4 + s) * 64 + lane) * 8);
            acc2[tt] = __builtin_amdgcn_mfma_f32_16x16x32_bf16(af2[s], bf, acc2[tt], 0, 0, 0);
        }
    }
#pragma unroll
    for (int tt = 0; tt < 4; tt++) {
        int t = half * 4 + tt;
        float bb = o2_b[t * 16 + l15];
#pragma unroll
        for (int r = 0; r < 4; r++) {
            int row = m16 + quad * 4 + r;
            int col = t * 16 + l15;
            x_s[col * 36 + row] = acc2[tt][r] + bb + x_s[col * 36 + row];
        }
    }
    __syncthreads();   // B4: x_s final

    // store, coalesced fp32 [c][n]
    {
        int c = tid >> 1, nh = (tid & 1) * 16;
        float4* dst = (float4*)(out + ((size_t)(b * 128 + c)) * 16384 + n0 + nh);
        const float4* sv = (const float4*)&x_s[c * 36 + nh];
#pragma unroll
        for (int i = 0; i < 4; i++) dst[i] = sv[i];
    }
}

// ---------------------------------------------------------------------------
extern "C" void kernel_launch(void* const* d_in, const int* in_sizes, int n_in,
                              void* d_out, int out_size, void* d_ws, size_t ws_size,
                              hipStream_t stream) {
    (void)in_sizes; (void)n_in; (void)out_size; (void)ws_size;
    const float* x     = (const float*)d_in[0];
    const float* qkv_w = (const float*)d_in[1];
    const float* qkv_b = (const float*)d_in[2];
    const float* o1_w  = (const float*)d_in[3];
    const float* o1_b  = (const float*)d_in[4];
    const float* o2_w  = (const float*)d_in[5];
    const float* o2_b  = (const float*)d_in[6];
    const float* klw   = (const float*)d_in[7];
    const float* klb   = (const float*)d_in[8];
    const float* vlw   = (const float*)d_in[9];
    const float* vlb   = (const float*)d_in[10];
    float* outp = (float*)d_out;

    char* ws = (char*)d_ws;
    u16*   wq    = (u16*)(ws + 32768);             // 49152 bf16 (96 KB)
    u16*   o1f   = (u16*)(ws + 131072);            // 16384 bf16 (32 KB)
    u16*   o2f   = (u16*)(ws + 163840);            // 16384 bf16 (32 KB)
    float* kvacc = (float*)(ws + 196608);          // 8*8*64*4 f32 (64 KB)

    hipMemsetAsync(kvacc, 0, 65536, stream);       // zero kv accumulator
    prep_kernel<<<320, 256, 0, stream>>>(qkv_w, o1_w, o2_w, wq, o1f, o2f);
    k1<<<2048, 512, 0, stream>>>(x, wq, qkv_b, klw, klb, vlw, vlb, kvacc);
    k2<<<4096, 256, 0, stream>>>(x, wq, qkv_b, kvacc, o1f, o2f, o1_b, o2_b, outp);
}

// Round 10
// 208.902 us; speedup vs baseline: 1.2704x; 1.2704x over previous
//
#include <hip/hip_runtime.h>
#include <hip/hip_bf16.h>

#define LN_EPS 1e-5f

typedef __bf16 bf16x8 __attribute__((ext_vector_type(8)));
typedef float  f32x4  __attribute__((ext_vector_type(4)));
typedef unsigned short u16;
typedef unsigned int u32;

__device__ __forceinline__ u16 f2bf(float f) {
    __bf16 b = (__bf16)f;
    return __builtin_bit_cast(u16, b);
}
__device__ __forceinline__ bf16x8 zero8() {
    bf16x8 v;
#pragma unroll
    for (int j = 0; j < 8; j++) v[j] = (__bf16)0.f;
    return v;
}
// tanh-form GELU: v * sigmoid(v*(1.59576912 + 0.07135482 v^2))
__device__ __forceinline__ float gelu_f(float v) {
    float t = v * fmaf(v * v, 0.0713548162726f, 1.5957691216057f);
    return v / (1.f + __expf(-t));
}

// ---------------------------------------------------------------------------
// prep: pack weights into bf16 MFMA B-fragment order (16x16x32).
// ---------------------------------------------------------------------------
__global__ __launch_bounds__(256) void prep_kernel(
    const float* __restrict__ qkv_w, const float* __restrict__ o1_w,
    const float* __restrict__ o2_w, u16* __restrict__ wq,
    u16* __restrict__ o1f, u16* __restrict__ o2f) {
    int i = blockIdx.x * 256 + threadIdx.x;
    if (i >= 81920) return;
    int j = i;
    const float* src;
    u16* dst;
    if (j < 49152) { src = qkv_w; dst = wq; }
    else if (j < 65536) { j -= 49152; src = o1_w; dst = o1f; }
    else { j -= 65536; src = o2_w; dst = o2f; }
    int jj = j & 7;
    int l  = (j >> 3) & 63;
    int s  = (j >> 9) & 3;
    int t  = j >> 11;
    int outc = t * 16 + (l & 15);
    int k    = s * 32 + ((l >> 4) & 3) * 8 + jj;
    dst[j] = f2bf(src[outc * 128 + k]);
}

// ---------------------------------------------------------------------------
// k1 (R10 = R8, proven): 512-thread straight-line, q-path removed, 4
// barriers, x_a in its own region, part written as plain stores.
// R9's atomicAdd-kv variant cross-XCD line-ping-ponged (105us, 4x writes).
// SESSION LAW: no loops / duplicated pipelines / reg-staging arrays across
// barriers -- R2, R4, R7 all spilled to scratch (+260..540MB sym traffic).
// grid 2048 = B * (N/64); block 512 (8 waves: 4 row-stripes x 2 head-halves)
// ---------------------------------------------------------------------------
__global__ __launch_bounds__(512, 8) void k1(
    const float* __restrict__ x, const u16* __restrict__ wq,
    const float* __restrict__ qkv_b,
    const float* __restrict__ klw, const float* __restrict__ klb,
    const float* __restrict__ vlw, const float* __restrict__ vlb,
    float* __restrict__ part) {
    __shared__ __align__(16) char Rbuf[51200];
    u16* x_a  = (u16*)Rbuf;            // [64 n][136] @0..17408 (live to B3)
    u16* kv_s = (u16*)(Rbuf + 17408);  // [64 n][264] @17408..51200
    u16* kT   = (u16*)Rbuf;            // [128 hd][72] @0..18432 (post-B3)
    u16* vT   = (u16*)(Rbuf + 18432);  // [128 hd][72] @18432..36864 (post-B3)

    const int tid  = threadIdx.x;
    const int lane = tid & 63;
    const int wv   = tid >> 6;
    const int stripe = wv >> 1;
    const int half   = wv & 1;
    const int bid  = blockIdx.x;
    const int b    = bid >> 8;
    const int n0   = (bid & 255) * 64;

    // phase 1: stage x -> x_a, packed b32 writes (conflict-free)
    {
        int cw  = tid & 63;     // channel pair
        int sub = tid >> 6;     // n octet
        const float* p0 = x + ((size_t)(b * 128 + 2 * cw)) * 16384 + n0 + sub * 8;
        const float* p1 = p0 + 16384;
        float4 a0 = ((const float4*)p0)[0], a1 = ((const float4*)p0)[1];
        float4 c0 = ((const float4*)p1)[0], c1 = ((const float4*)p1)[1];
        float av[8] = {a0.x, a0.y, a0.z, a0.w, a1.x, a1.y, a1.z, a1.w};
        float cv[8] = {c0.x, c0.y, c0.z, c0.w, c1.x, c1.y, c1.z, c1.w};
        u32* dst = (u32*)x_a;
#pragma unroll
        for (int j = 0; j < 8; j++)
            dst[(sub * 8 + j) * 68 + cw] = (u32)f2bf(av[j]) | ((u32)f2bf(cv[j]) << 16);
    }
    __syncthreads();   // B1: x_a visible

    const int m16  = stripe * 16;
    const int l15  = lane & 15;
    const int quad = lane >> 4;

    // phase 2+3 (merged): A-frags from x_a, then k,v GEMM writing kv_s --
    // disjoint LDS regions, so no barrier between.
    bf16x8 af[4];
#pragma unroll
    for (int s = 0; s < 4; s++)
        af[s] = *(const bf16x8*)&x_a[(m16 + l15) * 136 + s * 32 + quad * 8];

    const int tb = half * 12;
#pragma unroll
    for (int hh = 0; hh < 4; hh++) {
        const int tq = tb + 3 * hh;
        f32x4 ak  = (f32x4){0.f, 0.f, 0.f, 0.f};
        f32x4 avv = (f32x4){0.f, 0.f, 0.f, 0.f};
#pragma unroll
        for (int s = 0; s < 4; s++) {
            bf16x8 bk = *(const bf16x8*)(wq + (size_t)(((tq + 1) * 4 + s) * 64 + lane) * 8);
            bf16x8 bv = *(const bf16x8*)(wq + (size_t)(((tq + 2) * 4 + s) * 64 + lane) * 8);
            ak  = __builtin_amdgcn_mfma_f32_16x16x32_bf16(af[s], bk, ak, 0, 0, 0);
            avv = __builtin_amdgcn_mfma_f32_16x16x32_bf16(af[s], bv, avv, 0, 0, 0);
        }
        const int h = half * 4 + hh;
        float biask = qkv_b[(tq + 1) * 16 + l15];
        float biasv = qkv_b[(tq + 2) * 16 + l15];
#pragma unroll
        for (int r = 0; r < 4; r++) {
            int row = m16 + quad * 4 + r;
            kv_s[row * 264 + h * 32 + l15]      = f2bf(ak[r] + biask);
            kv_s[row * 264 + h * 32 + 16 + l15] = f2bf(avv[r] + biasv);
        }
    }
    __syncthreads();   // B2: kv_s visible

    // phase 4: per-row LN. thread = (head hL = wave, row = lane).
    const int hL = __builtin_amdgcn_readfirstlane(wv);
    const u16* rowp = &kv_s[lane * 264 + hL * 32];
    bf16x8 rk0 = *(const bf16x8*)(rowp);
    bf16x8 rk1 = *(const bf16x8*)(rowp + 8);
    bf16x8 rv0 = *(const bf16x8*)(rowp + 16);
    bf16x8 rv1 = *(const bf16x8*)(rowp + 24);
    __syncthreads();   // B3: kv_s (and x_a) dead -> kT/vT overlay safe

    {
        float kf[16], vf[16];
#pragma unroll
        for (int j = 0; j < 8; j++) {
            kf[j] = (float)rk0[j]; kf[8 + j] = (float)rk1[j];
            vf[j] = (float)rv0[j]; vf[8 + j] = (float)rv1[j];
        }
        float ksum = 0.f, ksq = 0.f, vsum = 0.f, vsq = 0.f;
#pragma unroll
        for (int d = 0; d < 16; d++) {
            ksum += kf[d]; ksq = fmaf(kf[d], kf[d], ksq);
            vsum += vf[d]; vsq = fmaf(vf[d], vf[d], vsq);
        }
        float km = ksum * (1.f / 16.f);
        float kvar = (ksq - 16.f * km * km) * (1.f / 15.f);
        kvar = kvar < 0.f ? 0.f : kvar;
        float kinv = 1.f / (sqrtf(kvar) + LN_EPS);
        float vm = vsum * (1.f / 16.f);
        float vvar = (vsq - 16.f * vm * vm) * (1.f / 15.f);
        vvar = vvar < 0.f ? 0.f : vvar;
        float vinv = 1.f / (sqrtf(vvar) + LN_EPS);
        const float* kwp = klw + hL * 16; const float* kbp = klb + hL * 16;
        const float* vwp = vlw + hL * 16; const float* vbp = vlb + hL * 16;
#pragma unroll
        for (int d = 0; d < 16; d++) {
            kT[(hL * 16 + d) * 72 + lane] = f2bf(fmaf((kf[d] - km) * kinv, kwp[d], kbp[d]));
            vT[(hL * 16 + d) * 72 + lane] = f2bf(fmaf((vf[d] - vm) * vinv, vwp[d], vbp[d]));
        }
    }
    __syncthreads();   // B4: kT/vT visible

    // phase 6: kv partial for head hL over all 64 rows: 2 MFMAs
    {
        const u16* ka = &kT[(hL * 16 + l15) * 72 + quad * 8];
        const u16* vb = &vT[(hL * 16 + l15) * 72 + quad * 8];
        bf16x8 A0 = *(const bf16x8*)(ka);
        bf16x8 A1 = *(const bf16x8*)(ka + 32);
        bf16x8 B0 = *(const bf16x8*)(vb);
        bf16x8 B1 = *(const bf16x8*)(vb + 32);
        f32x4 kv = __builtin_amdgcn_mfma_f32_16x16x32_bf16(A0, B0, (f32x4){0.f,0.f,0.f,0.f}, 0, 0, 0);
        kv = __builtin_amdgcn_mfma_f32_16x16x32_bf16(A1, B1, kv, 0, 0, 0);
        ((f32x4*)part)[(size_t)(bid * 8 + hL) * 64 + lane] = kv;
    }
}

// ---------------------------------------------------------------------------
// k_red: coalesced f32x4 reduction (R3, proven).
// grid 64 = b(8) x h(8); block 256; LDS combine.
// ---------------------------------------------------------------------------
__global__ __launch_bounds__(256) void k_red(const float* __restrict__ part,
                                             u16* __restrict__ kvf) {
    __shared__ f32x4 red[4][64];
    const int tid  = threadIdx.x;
    const int lane = tid & 63;
    const int wvq  = tid >> 6;
    const int b = blockIdx.x >> 3;
    const int h = blockIdx.x & 7;

    const f32x4* p = (const f32x4*)part;
    f32x4 s = (f32x4){0.f, 0.f, 0.f, 0.f};
#pragma unroll 8
    for (int tt = 0; tt < 64; tt++) {
        int t = wvq * 64 + tt;
        f32x4 v = p[((size_t)(b * 256 + t) * 8 + h) * 64 + lane];
        s += v;
    }
    red[wvq][lane] = s;
    __syncthreads();
    if (tid < 64) {
        f32x4 tot = red[0][lane];
#pragma unroll
        for (int w = 1; w < 4; w++) tot += red[w][lane];
#pragma unroll
        for (int r = 0; r < 4; r++) {
            int dk = (lane >> 4) * 4 + r;
            int dv = lane & 15;
            kvf[(size_t)(b * 8 + h) * 256 + (dk >> 3) * 128 + dv * 8 + (dk & 7)] =
                f2bf(tot[r] * (1.f / 16384.f));
        }
    }
}

// ---------------------------------------------------------------------------
// k2 (R10): R8 structure + x_s bank-conflict fix. x_s transposed from
// [c:128][36] to [n:32][c:132] (132%32=4). The old layout's stage wrote
// float4s at float-offset 72*lane -> bank 8*lane%32 -> 16-way conflict on
// all 8 staging stores (SQ_LDS_BANK_CONFLICT 2.23M, 4.3x k1's). New layout:
// stage = 8 float2 writes at bank 2*lane (2-way = free); ret-add read, o2
// RMW, and final-store gather all <=2 lanes/bank (store becomes 16 scalar
// b32 reads, conflict-free). No new register state, no barrier changes.
// LDS 34304 (a_s 8704 + x_a16/h_s 8704 + x_s 16896), 4 blocks/CU.
// grid 4096 = B*(N/32); block 256 (2 stripes x 2 halves).
// ---------------------------------------------------------------------------
__global__ __launch_bounds__(256, 4) void k2(
    const float* __restrict__ x, const u16* __restrict__ wq,
    const float* __restrict__ qkv_b,
    const u16* __restrict__ kvf, const u16* __restrict__ o1f,
    const u16* __restrict__ o2f, const float* __restrict__ o1_b,
    const float* __restrict__ o2_b, float* __restrict__ out) {
    __shared__ u16 a_s[32 * 136];      // q -> ret (A-layout)
    __shared__ u16 x_a16[32 * 136];    // x A-layout; becomes h1 (h_s) later
    __shared__ float x_s[32 * 132];    // x [n][c]; becomes out in place

    u16* h_s = x_a16;                  // alias: h1 buffer (post-B2)

    const int tid  = threadIdx.x;
    const int lane = tid & 63;
    const int wv   = tid >> 6;
    const int stripe = wv >> 1;
    const int half   = wv & 1;
    const int bid  = blockIdx.x;
    const int b    = bid >> 9;
    const int n0   = (bid & 511) * 32;

    const int m16  = stripe * 16;
    const int l15  = lane & 15;
    const int quad = lane >> 4;
    const bool act = quad < 2;

    // hoisted kv B-frags (tiny, L2/L3-resident)
    bf16x8 kvb[4];
    {
#pragma unroll
        for (int hh = 0; hh < 4; hh++) {
            int h = half * 4 + hh;
            if (act) {
                kvb[hh] = *(const bf16x8*)(kvf + (size_t)(b * 8 + h) * 256 + quad * 128 + l15 * 8);
            } else {
                kvb[hh] = zero8();
            }
        }
    }

    // stage x -> x_s (f32, [n][c], float2 = adjacent channels) AND
    // x_a16 (bf16 A-layout [n][136])
    {
        int cw  = tid & 63;     // channel pair
        int sub = tid >> 6;     // n octet (0..3)
        const float* p0 = x + ((size_t)(b * 128 + 2 * cw)) * 16384 + n0 + sub * 8;
        const float* p1 = p0 + 16384;
        float4 a0 = ((const float4*)p0)[0], a1 = ((const float4*)p0)[1];
        float4 c0 = ((const float4*)p1)[0], c1 = ((const float4*)p1)[1];
        float av[8] = {a0.x, a0.y, a0.z, a0.w, a1.x, a1.y, a1.z, a1.w};
        float cv[8] = {c0.x, c0.y, c0.z, c0.w, c1.x, c1.y, c1.z, c1.w};
        u32* da = (u32*)x_a16;
#pragma unroll
        for (int j = 0; j < 8; j++) {
            da[(sub * 8 + j) * 68 + cw] = (u32)f2bf(av[j]) | ((u32)f2bf(cv[j]) << 16);
            *(float2*)&x_s[(sub * 8 + j) * 132 + 2 * cw] = (float2){av[j], cv[j]};
        }
    }
    __syncthreads();   // B1: x_s, x_a16 visible

    // q GEMM: reads x_a16 (cross-wave, covered by B1); q -> a_s own block
    {
        bf16x8 axf[4];
#pragma unroll
        for (int s = 0; s < 4; s++)
            axf[s] = *(const bf16x8*)&x_a16[(m16 + l15) * 136 + s * 32 + quad * 8];
#pragma unroll
        for (int hh = 0; hh < 4; hh++) {
            int h = half * 4 + hh;
            int tq = 3 * h;
            f32x4 aq = (f32x4){0.f, 0.f, 0.f, 0.f};
#pragma unroll
            for (int s = 0; s < 4; s++) {
                bf16x8 bq = *(const bf16x8*)(wq + (size_t)((tq * 4 + s) * 64 + lane) * 8);
                aq = __builtin_amdgcn_mfma_f32_16x16x32_bf16(axf[s], bq, aq, 0, 0, 0);
            }
            float biasq = qkv_b[tq * 16 + l15];
#pragma unroll
            for (int r = 0; r < 4; r++)
                a_s[(m16 + quad * 4 + r) * 136 + h * 16 + l15] = f2bf(aq[r] + biasq);
        }
    }
    // read back q A-frags (same-wave block: rows own stripe, cols own heads)
    bf16x8 qf[4];
#pragma unroll
    for (int hh = 0; hh < 4; hh++) {
        int h = half * 4 + hh;
        if (act) qf[hh] = *(const bf16x8*)&a_s[(m16 + l15) * 136 + h * 16 + quad * 8];
        else     qf[hh] = zero8();
    }

    // av per head (4 heads per wave), ret = av + x  (overwrites own a_s block)
#pragma unroll
    for (int hh = 0; hh < 4; hh++) {
        int h = half * 4 + hh;
        f32x4 acc = __builtin_amdgcn_mfma_f32_16x16x32_bf16(
            qf[hh], kvb[hh], (f32x4){0.f,0.f,0.f,0.f}, 0, 0, 0);
#pragma unroll
        for (int r = 0; r < 4; r++) {
            float rv = acc[r] + x_s[(m16 + quad * 4 + r) * 132 + h * 16 + l15];
            a_s[(m16 + quad * 4 + r) * 136 + h * 16 + l15] = f2bf(rv);
        }
    }
    __syncthreads();   // B2: a_s = ret visible; x_a16 reads all done

    // o1: 4 t-tiles per wave over full-128 rows; h1 -> h_s (retired x_a16)
    bf16x8 af2[4];
#pragma unroll
    for (int s = 0; s < 4; s++)
        af2[s] = *(const bf16x8*)&a_s[(m16 + l15) * 136 + s * 32 + quad * 8];
    f32x4 acc2[4];
#pragma unroll
    for (int t = 0; t < 4; t++) acc2[t] = (f32x4){0.f,0.f,0.f,0.f};
#pragma unroll
    for (int tt = 0; tt < 4; tt++) {
        int t = half * 4 + tt;
#pragma unroll
        for (int s = 0; s < 4; s++) {
            bf16x8 bf = *(const bf16x8*)(o1f + (size_t)((t * 4 + s) * 64 + lane) * 8);
            acc2[tt] = __builtin_amdgcn_mfma_f32_16x16x32_bf16(af2[s], bf, acc2[tt], 0, 0, 0);
        }
    }
#pragma unroll
    for (int tt = 0; tt < 4; tt++) {
        float bb = o1_b[(half * 4 + tt) * 16 + l15];
#pragma unroll
        for (int r = 0; r < 4; r++) {
            float gg = gelu_f(acc2[tt][r] + bb);
            h_s[(m16 + quad * 4 + r) * 136 + (half * 4 + tt) * 16 + l15] = f2bf(gg);
        }
    }
    __syncthreads();   // B3: h_s visible

    // o2: out = h1 @ o2^T + b2 + x  (in place in x_s, [n][c])
#pragma unroll
    for (int s = 0; s < 4; s++)
        af2[s] = *(const bf16x8*)&h_s[(m16 + l15) * 136 + s * 32 + quad * 8];
#pragma unroll
    for (int t = 0; t < 4; t++) acc2[t] = (f32x4){0.f,0.f,0.f,0.f};
#pragma unroll
    for (int tt = 0; tt < 4; tt++) {
        int t = half * 4 + tt;
#pragma unroll
        for (int s = 0; s < 4; s++) {
            bf16x8 bf = *(const bf16x8*)(o2f + (size_t)((t * 4 + s) * 64 + lane) * 8);
            acc2[tt] = __builtin_amdgcn_mfma_f32_16x16x32_bf16(af2[s], bf, acc2[tt], 0, 0, 0);
        }
    }
#pragma unroll
    for (int tt = 0; tt < 4; tt++) {
        int t = half * 4 + tt;
        float bb = o2_b[t * 16 + l15];
#pragma unroll
        for (int r = 0; r < 4; r++) {
            int row = m16 + quad * 4 + r;
            int col = t * 16 + l15;
            x_s[row * 132 + col] = acc2[tt][r] + bb + x_s[row * 132 + col];
        }
    }
    __syncthreads();   // B4: x_s final

    // store, coalesced fp32 [c][n] to global; gather scalar from x_s [n][c]
    {
        int c = tid >> 1, nh = (tid & 1) * 16;
        float4* dst = (float4*)(out + ((size_t)(b * 128 + c)) * 16384 + n0 + nh);
#pragma unroll
        for (int i = 0; i < 4; i++) {
            float4 sv;
            sv.x = x_s[(nh + 4 * i + 0) * 132 + c];
            sv.y = x_s[(nh + 4 * i + 1) * 132 + c];
            sv.z = x_s[(nh + 4 * i + 2) * 132 + c];
            sv.w = x_s[(nh + 4 * i + 3) * 132 + c];
            dst[i] = sv;
        }
    }
}

// ---------------------------------------------------------------------------
extern "C" void kernel_launch(void* const* d_in, const int* in_sizes, int n_in,
                              void* d_out, int out_size, void* d_ws, size_t ws_size,
                              hipStream_t stream) {
    (void)in_sizes; (void)n_in; (void)out_size; (void)ws_size;
    const float* x     = (const float*)d_in[0];
    const float* qkv_w = (const float*)d_in[1];
    const float* qkv_b = (const float*)d_in[2];
    const float* o1_w  = (const float*)d_in[3];
    const float* o1_b  = (const float*)d_in[4];
    const float* o2_w  = (const float*)d_in[5];
    const float* o2_b  = (const float*)d_in[6];
    const float* klw   = (const float*)d_in[7];
    const float* klb   = (const float*)d_in[8];
    const float* vlw   = (const float*)d_in[9];
    const float* vlb   = (const float*)d_in[10];
    float* outp = (float*)d_out;

    char* ws = (char*)d_ws;
    u16*   kvf  = (u16*)(ws);                     // 16384 bf16 (32 KB)
    u16*   wq   = (u16*)(ws + 32768);             // 49152 bf16 (96 KB)
    u16*   o1f  = (u16*)(ws + 131072);            // 16384 bf16 (32 KB)
    u16*   o2f  = (u16*)(ws + 163840);            // 16384 bf16 (32 KB)
    float* part = (float*)(ws + 196608);          // 2048*2048 f (16 MB)

    prep_kernel<<<320, 256, 0, stream>>>(qkv_w, o1_w, o2_w, wq, o1f, o2f);
    k1<<<2048, 512, 0, stream>>>(x, wq, qkv_b, klw, klb, vlw, vlb, part);
    k_red<<<64, 256, 0, stream>>>(part, kvf);
    k2<<<4096, 256, 0, stream>>>(x, wq, qkv_b, kvf, o1f, o2f, o1_b, o2_b, outp);
}